// Round 3
// baseline (397.976 us; speedup 1.0000x reference)
//
#include <hip/hip_runtime.h>
#include <cmath>

typedef __attribute__((ext_vector_type(8))) short short8;
typedef __attribute__((ext_vector_type(4))) float floatx4;
typedef __attribute__((ext_vector_type(2))) float floatx2;
typedef __attribute__((ext_vector_type(4))) int intx4;
typedef __attribute__((ext_vector_type(2))) int intx2;

#define N_G 50000
#define E_G 800000
#define N_S 10000
#define E_S 160000
#define NT (N_G + N_S)      // 60000 combined nodes
#define ET (E_G + E_S)      // 960000 combined edges
#define BATCH 8
#define STRIDE 64           // fixed CSR stride (deg ~ Poisson(16); P(>64) ~ 1e-18)
#define FPASS 8             // fill: XCD-aligned dst groups

__device__ __forceinline__ short f2b(float f) {
    unsigned u = __builtin_bit_cast(unsigned, f);
    u += 0x7FFF + ((u >> 16) & 1);   // RNE
    return (short)(u >> 16);
}
// 8 fp8 bytes -> 8 bf16 (in-register root-path dequant)
__device__ __forceinline__ short8 fp8x8_to_bf16(intx2 w) {
    floatx2 f0 = __builtin_amdgcn_cvt_pk_f32_fp8(w[0], false);
    floatx2 f1 = __builtin_amdgcn_cvt_pk_f32_fp8(w[0], true);
    floatx2 f2 = __builtin_amdgcn_cvt_pk_f32_fp8(w[1], false);
    floatx2 f3 = __builtin_amdgcn_cvt_pk_f32_fp8(w[1], true);
    short8 r;
    r[0]=f2b(f0[0]); r[1]=f2b(f0[1]); r[2]=f2b(f1[0]); r[3]=f2b(f1[1]);
    r[4]=f2b(f2[0]); r[5]=f2b(f2[1]); r[6]=f2b(f3[0]); r[7]=f2b(f3[1]);
    return r;
}
// async global->LDS, 16B per lane (wave-uniform base + lane*16 linear dest)
__device__ __forceinline__ void gload_lds16(const void* g, void* l) {
    __builtin_amdgcn_global_load_lds(
        (const __attribute__((address_space(1))) unsigned int*)g,
        (__attribute__((address_space(3))) unsigned int*)l, 16, 0, 0);
}

// ---------------- init: zeros + bounds + X0 fp8 + weight repack (merged) ------
struct RepArgs { const float* Wr[6]; const float* Wn[6]; short* dst[6]; int cin[6]; int nk[6]; int groups[6]; };
__global__ void init_kernel(const float* __restrict__ gx, const float* __restrict__ sx,
                            unsigned char* __restrict__ X0_8,
                            int* __restrict__ dcount, float* __restrict__ pooled,
                            const int* __restrict__ g_batch, const int* __restrict__ s_batch,
                            int* __restrict__ starts, RepArgs ra, int total_groups) {
    int t = blockIdx.x * blockDim.x + threadIdx.x;
    if (t < NT * 16) {
        size_t e = (size_t)t * 4;
        const float* src = (e < (size_t)N_G * 64) ? (gx + e) : (sx + (e - (size_t)N_G * 64));
        floatx4 v = *(const floatx4*)src;
        int w8 = 0;
        w8 = __builtin_amdgcn_cvt_pk_fp8_f32(v[0], v[1], w8, false);
        w8 = __builtin_amdgcn_cvt_pk_fp8_f32(v[2], v[3], w8, true);
        *(unsigned int*)(X0_8 + e) = (unsigned int)w8;
    }
    if (t < NT) dcount[t] = 0;
    if (t < 16 * 192) pooled[t] = 0.f;
    if (t <= 16) {
        int b = t;
        if (b == 16) { starts[16] = NT; }
        else {
            int key, n, base;
            const int* arr;
            if (b < 8) { arr = g_batch; n = N_G; key = b; base = 0; }
            else       { arr = s_batch; n = N_S; key = b - 8; base = N_G; }
            int lo = 0, hi = n;
            while (lo < hi) { int mid = (lo + hi) >> 1; if (arr[mid] < key) lo = mid + 1; else hi = mid; }
            starts[b] = base + lo;
        }
    }
    // weight repack: fp32 [o][c] -> bf16 MFMA-fragment order
    if (t < total_groups) {
        int seg = 0, off = t;
        while (seg < 5 && off >= ra.groups[seg]) { off -= ra.groups[seg]; ++seg; }
        int CIN = ra.cin[seg], NK = ra.nk[seg];
        int lane = off & 63;
        int rest = off >> 6;
        int tt = rest % NK;
        int ot = rest / NK;
        int o = ot * 16 + (lane & 15);
        int kk = tt * 32 + (lane >> 4) * 8;
        const float* src = (kk < CIN) ? (ra.Wr[seg] + (size_t)o * CIN + kk)
                                      : (ra.Wn[seg] + (size_t)o * CIN + (kk - CIN));
        floatx4 u0 = *(const floatx4*)src;
        floatx4 u1 = *(const floatx4*)(src + 4);
        short8 d;
        d[0]=f2b(u0[0]); d[1]=f2b(u0[1]); d[2]=f2b(u0[2]); d[3]=f2b(u0[3]);
        d[4]=f2b(u1[0]); d[5]=f2b(u1[1]); d[6]=f2b(u1[2]); d[7]=f2b(u1[3]);
        *(short8*)(ra.dst[seg] + (size_t)off * 8) = d;
    }
}

// ---------------- stride-CSR fill: XCD-aligned dst groups ----------------
__global__ void fill_kernel(const int* __restrict__ g_ei, const int* __restrict__ s_ei,
                            int* __restrict__ dcount, int* __restrict__ csr) {
    int pass = blockIdx.x & (FPASS - 1);
    int lb   = blockIdx.x >> 3;
    int t = lb * blockDim.x + threadIdx.x;
    if (t >= ET) return;
    int dst;
    if (t < E_G) dst = g_ei[E_G + t];
    else         dst = s_ei[E_S + (t - E_G)] + N_G;
    int lo = pass * (NT / FPASS);
    int hi = lo + (NT / FPASS);
    if (dst < lo || dst >= hi) return;
    int src;
    if (t < E_G) src = g_ei[t];
    else         src = s_ei[t - E_G] + N_G;
    int slot = atomicAdd(&dcount[dst], 1);
    if (slot < STRIDE) csr[(size_t)dst * STRIDE + slot] = src;
}

// ---------------- fp8 gather aggregation (all layers); bf16 out -------------
template<int C>
__global__ void agg8_kernel(const unsigned char* __restrict__ x8, const int* __restrict__ dcount,
                            const int* __restrict__ csr, short* __restrict__ out) {
    constexpr int C16 = C / 16;
    int t = blockIdx.x * blockDim.x + threadIdx.x;
    if (t >= NT * C16) return;
    int node = t / C16;
    int ch   = t % C16;
    int e0 = node * STRIDE;
    int e1 = e0 + min(dcount[node], STRIDE);
    float acc[16];
    #pragma unroll
    for (int j = 0; j < 16; ++j) acc[j] = 0.f;
    for (int e = e0; e < e1; ++e) {
        int s = csr[e];
        intx4 w = *(const intx4*)(x8 + (size_t)s * C + ch * 16);
        #pragma unroll
        for (int q = 0; q < 4; ++q) {
            floatx2 f0 = __builtin_amdgcn_cvt_pk_f32_fp8(w[q], false);
            floatx2 f1 = __builtin_amdgcn_cvt_pk_f32_fp8(w[q], true);
            acc[q * 4 + 0] += f0[0];
            acc[q * 4 + 1] += f0[1];
            acc[q * 4 + 2] += f1[0];
            acc[q * 4 + 3] += f1[1];
        }
    }
    short8 o0, o1;
    #pragma unroll
    for (int j = 0; j < 8; ++j) { o0[j] = f2b(acc[j]); o1[j] = f2b(acc[8 + j]); }
    short8* q = (short8*)(out + (size_t)node * C + ch * 16);
    q[0] = o0; q[1] = o1;
}

// ---------------- dual-GEMM + bias + ELU; column-split persistent weights ----
// v3: grid = C col-slices x (RGg + RGs) row-groups; block stages ONE 32KB
// weight slice (async, single barrier) then waves free-run over row-tiles
// with NO further barriers. Branch-partitioned grid (g rows vs s rows), so
// every block is weight-uniform. MROW row-tiles per wave-unit share each
// ds_read; k-split keeps A-fragment VGPR use at 64.
template<int CIN, int COUT, int OT, int MROW, bool POOL>
__global__ __launch_bounds__(256) void gemm_elu_kernel(
        const short* __restrict__ A1, const unsigned char* __restrict__ A2_8,
        const short* __restrict__ gWF, const short* __restrict__ sWF,
        const float* __restrict__ gB, const float* __restrict__ sB,
        unsigned char* __restrict__ out8,
        float* __restrict__ pooled, const int* __restrict__ starts,
        int RGg, int RGs) {
    constexpr int NK  = CIN / 16;            // k-chunks (K = 2*CIN, 32 per MFMA)
    constexpr int TILE_SH = NK * 512;        // shorts per output-tile weight block
    constexpr int CH_SH = OT * TILE_SH;      // 16384 shorts = 32KB for all layers
    constexpr int SREG = CH_SH / 2048;       // 16B async issues per thread
    constexpr int KH   = (NK > 8) ? 2 : 1;   // k-split halves A register pressure
    constexpr int NKH  = NK / KH;
    constexpr int TG = N_G / 16, TS = (NT - N_G) / 16;
    __shared__ short lds[CH_SH];

    int RB = RGg + RGs;
    int slice = blockIdx.x / RB;
    int r = blockIdx.x - slice * RB;
    bool isg = (r < RGg);
    int rpart = isg ? r : (r - RGg);
    int baseT = isg ? 0 : TG;
    int Tpart = isg ? TG : TS;
    int Wpart = (isg ? RGg : RGs) * 4;
    const short* WF = (isg ? gWF : sWF) + (size_t)slice * CH_SH;
    const float* bias = isg ? gB : sB;

    // stage this block's 32KB weight slice (async -> barrier)
    {
        const short* src = WF + threadIdx.x * 8;
        short* dst = &lds[threadIdx.x * 8];
        #pragma unroll
        for (int i = 0; i < SREG; ++i)
            gload_lds16(src + i * 2048, dst + i * 2048);
    }
    __syncthreads();   // drains vmcnt; weights resident for block lifetime

    int wave = threadIdx.x >> 6;
    int lane = threadIdx.x & 63;
    int id = lane & 15, quad = lane >> 4;
    int units = (Tpart + MROW - 1) / MROW;

    for (int u = rpart * 4 + wave; u < units; u += Wpart) {
        int tl[MROW]; bool act[MROW];
        #pragma unroll
        for (int m = 0; m < MROW; ++m) {
            int ti = u * MROW + m;
            act[m] = (ti < Tpart);
            tl[m] = baseT + (act[m] ? ti : (Tpart - 1));
        }
        floatx4 acc[MROW][OT];
        #pragma unroll
        for (int m = 0; m < MROW; ++m)
            #pragma unroll
            for (int o = 0; o < OT; ++o) acc[m][o] = floatx4{0.f, 0.f, 0.f, 0.f};

        for (int kh = 0; kh < KH; ++kh) {
            short8 a[MROW][NKH];
            #pragma unroll
            for (int m = 0; m < MROW; ++m) {
                int arow = tl[m] * 16 + id;
                #pragma unroll
                for (int t = 0; t < NKH; ++t) {
                    int kk = (kh * NKH + t) * 32 + quad * 8;
                    if (kk < CIN) {
                        a[m][t] = *(const short8*)(A1 + (size_t)arow * CIN + kk);
                    } else {
                        intx2 w = *(const intx2*)(A2_8 + (size_t)arow * CIN + (kk - CIN));
                        a[m][t] = fp8x8_to_bf16(w);
                    }
                }
            }
            #pragma unroll
            for (int otl = 0; otl < OT; ++otl) {
                #pragma unroll
                for (int t = 0; t < NKH; ++t) {
                    short8 b = *(const short8*)(&lds[((size_t)otl * NK + kh * NKH + t) * 512 + lane * 8]);
                    #pragma unroll
                    for (int m = 0; m < MROW; ++m)
                        acc[m][otl] = __builtin_amdgcn_mfma_f32_16x16x32_bf16(a[m][t], b, acc[m][otl], 0, 0, 0);
                }
            }
        }
        // epilogue
        #pragma unroll
        for (int m = 0; m < MROW; ++m) {
            if (!act[m]) continue;
            int r0 = tl[m] * 16;
            int seg0 = 0, seg1 = 0;
            if (POOL) {
                while (seg0 < 15 && starts[seg0 + 1] <= r0) ++seg0;
                seg1 = seg0;
                while (seg1 < 15 && starts[seg1 + 1] <= r0 + 15) ++seg1;
            }
            #pragma unroll
            for (int otl = 0; otl < OT; ++otl) {
                int o = (slice * OT + otl) * 16 + id;
                float bv = bias[o];
                float vr[4];
                #pragma unroll
                for (int rr = 0; rr < 4; ++rr) {
                    float v = acc[m][otl][rr] + bv;
                    vr[rr] = (v > 0.f) ? v : (__expf(v) - 1.f);
                }
                if (!POOL) {
                    #pragma unroll
                    for (int rr = 0; rr < 4; ++rr) {
                        int nrow = r0 + quad * 4 + rr;   // C/D: col=lane&15, row=quad*4+reg
                        int w8 = __builtin_amdgcn_cvt_pk_fp8_f32(vr[rr], vr[rr], 0, false);
                        out8[(size_t)nrow * COUT + o] = (unsigned char)(w8 & 0xFF);
                    }
                } else if (seg0 == seg1) {
                    float vsum = vr[0] + vr[1] + vr[2] + vr[3];
                    vsum += __shfl_down(vsum, 32, 64);
                    vsum += __shfl_down(vsum, 16, 64);
                    if (lane < 16) atomicAdd(&pooled[seg0 * 192 + o], vsum);
                } else {
                    #pragma unroll
                    for (int rr = 0; rr < 4; ++rr) {
                        int nrow = r0 + quad * 4 + rr;
                        int sg = seg0;
                        while (sg < seg1 && starts[sg + 1] <= nrow) ++sg;
                        atomicAdd(&pooled[sg * 192 + o], vr[rr]);
                    }
                }
            }
        }
    }
}

// ---------------- MLP layer 1: one wave per (b,o); builds x on the fly ----------
__global__ __launch_bounds__(256) void mlp1_kernel(
        const float* __restrict__ pooled, const int* __restrict__ starts,
        const float* __restrict__ point, const float* __restrict__ W,
        const float* __restrict__ bias, float* __restrict__ out) {
    int wave = (blockIdx.x * blockDim.x + threadIdx.x) >> 6;
    int lane = threadIdx.x & 63;
    if (wave >= BATCH * 600) return;
    int b = wave / 600, o = wave % 600;
    float invg = 1.f / (float)max(starts[b + 1] - starts[b], 1);
    float invs = 1.f / (float)max(starts[9 + b] - starts[8 + b], 1);
    const float* w = W + (size_t)o * 448;
    float acc = 0.f;
    for (int i = lane; i < 448; i += 64) {
        float x;
        if (i < 192)      x = pooled[b * 192 + i] * invg;
        else if (i < 384) x = pooled[(8 + b) * 192 + (i - 192)] * invs;
        else              x = point[b * 64 + (i - 384)];
        acc += x * w[i];
    }
    #pragma unroll
    for (int off = 32; off > 0; off >>= 1) acc += __shfl_down(acc, off, 64);
    if (lane == 0) out[wave] = fmaxf(acc + bias[o], 0.f);
}

// ---------------- dense layer: one wave per output neuron ----------------
__global__ __launch_bounds__(256) void dense_wave_kernel(
        const float* __restrict__ in, const float* __restrict__ W,
        const float* __restrict__ bias, float* __restrict__ out,
        int I, int O, int relu) {
    int wave = (blockIdx.x * blockDim.x + threadIdx.x) >> 6;
    int lane = threadIdx.x & 63;
    if (wave >= BATCH * O) return;
    int b = wave / O, o = wave % O;
    const float* x = in + (size_t)b * I;
    const float* w = W + (size_t)o * I;
    float acc = 0.f;
    for (int i = lane; i < I; i += 64) acc += x[i] * w[i];
    #pragma unroll
    for (int off = 32; off > 0; off >>= 1) acc += __shfl_down(acc, off, 64);
    if (lane == 0) {
        acc += bias[o];
        if (relu) acc = fmaxf(acc, 0.f);
        out[wave] = acc;
    }
}

extern "C" void kernel_launch(void* const* d_in, const int* in_sizes, int n_in,
                              void* d_out, int out_size, void* d_ws, size_t ws_size,
                              hipStream_t stream) {
    const float* graph_x = (const float*)d_in[0];
    const float* sub_x   = (const float*)d_in[1];
    const float* point   = (const float*)d_in[2];
    const int*   g_ei    = (const int*)d_in[3];
    const int*   g_batch = (const int*)d_in[4];
    const int*   s_ei    = (const int*)d_in[5];
    const int*   s_batch = (const int*)d_in[6];
    const float* gB1=(const float*)d_in[9],  *gB2=(const float*)d_in[12], *gB3=(const float*)d_in[15];
    const float* sB1=(const float*)d_in[18], *sB2=(const float*)d_in[21], *sB3=(const float*)d_in[24];
    const float* l1W=(const float*)d_in[25], *l1b=(const float*)d_in[26];
    const float* l2W=(const float*)d_in[27], *l2b=(const float*)d_in[28];
    const float* l3W=(const float*)d_in[29], *l3b=(const float*)d_in[30];

    char* ws = (char*)d_ws;
    size_t off = 0;
    auto alloc = [&](size_t bytes) -> char* {
        char* p = ws + off;
        off = (off + bytes + 255) & ~(size_t)255;
        return p;
    };
    int* dcount = (int*)alloc((size_t)NT * 4);
    int* csr = (int*)alloc((size_t)NT * STRIDE * 4);   // 15.36 MB stride-CSR

    // fragment-ordered bf16 weight slab: per layer COUT*2*CIN elems
    const int fsz[3] = {128 * 2 * 64, 256 * 2 * 128, 192 * 2 * 256};
    short* wfrag = (short*)alloc((size_t)(fsz[0] + fsz[1] + fsz[2]) * 2 * 2);
    short* gWF[3], *sWF[3];
    { size_t o2 = 0;
      for (int l = 0; l < 3; ++l) { gWF[l] = wfrag + o2; o2 += fsz[l]; }
      for (int l = 0; l < 3; ++l) { sWF[l] = wfrag + o2; o2 += fsz[l]; } }

    unsigned char* X0_8 = (unsigned char*)alloc((size_t)NT * 64);
    short* agg = (short*)alloc((size_t)NT * 256 * 2);
    unsigned char* h1_8 = (unsigned char*)alloc((size_t)NT * 128);
    unsigned char* h2_8 = (unsigned char*)alloc((size_t)NT * 256);

    float* pooled = (float*)alloc(16 * 192 * 4);
    int* starts = (int*)alloc(17 * 4);
    float* mlp_h1 = (float*)alloc(BATCH * 600 * 4);
    float* mlp_h2 = (float*)alloc(BATCH * 256 * 4);

    // weight repack args (merged into init)
    RepArgs ra;
    const int cin_l[3] = {64, 128, 256};
    const int nk_l[3]  = {4, 8, 16};
    const int not_l[3] = {8, 16, 12};
    const int wr_idx[6] = {7, 10, 13, 16, 19, 22};
    int total_groups = 0;
    for (int s = 0; s < 6; ++s) {
        int l = s % 3;
        ra.Wr[s] = (const float*)d_in[wr_idx[s]];
        ra.Wn[s] = (const float*)d_in[wr_idx[s] + 1];
        ra.dst[s] = (s < 3) ? gWF[l] : sWF[l];
        ra.cin[s] = cin_l[l];
        ra.nk[s] = nk_l[l];
        ra.groups[s] = not_l[l] * nk_l[l] * 64;
        total_groups += ra.groups[s];
    }

    init_kernel<<<(NT * 16 + 255) / 256, 256, 0, stream>>>(graph_x, sub_x, X0_8, dcount,
                                                           pooled, g_batch, s_batch, starts,
                                                           ra, total_groups);

    fill_kernel<<<((ET + 255) / 256) * FPASS, 256, 0, stream>>>(g_ei, s_ei, dcount, csr);

    // grids: L1 C=1 (MROW=1): 782+157 = 939 blocks
    //        L2 C=4 (MROW=2): 4*(391+79) = 1880 blocks
    //        L3 C=6 (MROW=2): 6*(391+79) = 2820 blocks
    agg8_kernel<64><<<(NT * 4 + 255) / 256, 256, 0, stream>>>(X0_8, dcount, csr, agg);
    gemm_elu_kernel<64, 128, 8, 1, false><<<939, 256, 0, stream>>>(
        agg, X0_8, gWF[0], sWF[0], gB1, sB1, h1_8, nullptr, nullptr, 782, 157);
    agg8_kernel<128><<<(NT * 8 + 255) / 256, 256, 0, stream>>>(h1_8, dcount, csr, agg);
    gemm_elu_kernel<128, 256, 4, 2, false><<<1880, 256, 0, stream>>>(
        agg, h1_8, gWF[1], sWF[1], gB2, sB2, h2_8, nullptr, nullptr, 391, 79);
    agg8_kernel<256><<<(NT * 16 + 255) / 256, 256, 0, stream>>>(h2_8, dcount, csr, agg);
    gemm_elu_kernel<256, 192, 2, 2, true><<<2820, 256, 0, stream>>>(
        agg, h2_8, gWF[2], sWF[2], gB3, sB3, nullptr, pooled, starts, 391, 79);

    mlp1_kernel<<<(BATCH * 600 + 3) / 4, 256, 0, stream>>>(pooled, starts, point, l1W, l1b, mlp_h1);
    dense_wave_kernel<<<(BATCH * 256 + 3) / 4, 256, 0, stream>>>(mlp_h1, l2W, l2b, mlp_h2, 600, 256, 1);
    dense_wave_kernel<<<(BATCH * 64 + 3) / 4, 256, 0, stream>>>(mlp_h2, l3W, l3b, (float*)d_out, 256, 64, 0);
}

// Round 4
// 393.212 us; speedup vs baseline: 1.0121x; 1.0121x over previous
//
#include <hip/hip_runtime.h>
#include <cmath>

typedef __attribute__((ext_vector_type(8))) short short8;
typedef __attribute__((ext_vector_type(4))) float floatx4;
typedef __attribute__((ext_vector_type(2))) float floatx2;
typedef __attribute__((ext_vector_type(4))) int intx4;
typedef __attribute__((ext_vector_type(2))) int intx2;

#define N_G 50000
#define E_G 800000
#define N_S 10000
#define E_S 160000
#define NT (N_G + N_S)      // 60000 combined nodes
#define ET (E_G + E_S)      // 960000 combined edges
#define BATCH 8
#define STRIDE 64           // fixed CSR stride (deg ~ Poisson(16); P(>64) ~ 1e-18)
#define FPASS 8             // fill: XCD-aligned dst groups

__device__ __forceinline__ short f2b(float f) {
    unsigned u = __builtin_bit_cast(unsigned, f);
    u += 0x7FFF + ((u >> 16) & 1);   // RNE
    return (short)(u >> 16);
}
// 8 fp8 bytes -> 8 bf16 (in-register root-path dequant)
__device__ __forceinline__ short8 fp8x8_to_bf16(intx2 w) {
    floatx2 f0 = __builtin_amdgcn_cvt_pk_f32_fp8(w[0], false);
    floatx2 f1 = __builtin_amdgcn_cvt_pk_f32_fp8(w[0], true);
    floatx2 f2 = __builtin_amdgcn_cvt_pk_f32_fp8(w[1], false);
    floatx2 f3 = __builtin_amdgcn_cvt_pk_f32_fp8(w[1], true);
    short8 r;
    r[0]=f2b(f0[0]); r[1]=f2b(f0[1]); r[2]=f2b(f1[0]); r[3]=f2b(f1[1]);
    r[4]=f2b(f2[0]); r[5]=f2b(f2[1]); r[6]=f2b(f3[0]); r[7]=f2b(f3[1]);
    return r;
}

// ---------------- init: zeros + bounds + X0 fp8 + weight repack (merged) ------
struct RepArgs { const float* Wr[6]; const float* Wn[6]; short* dst[6]; int cin[6]; int nk[6]; int groups[6]; };
__global__ void init_kernel(const float* __restrict__ gx, const float* __restrict__ sx,
                            unsigned char* __restrict__ X0_8,
                            int* __restrict__ dcount, float* __restrict__ pooled,
                            const int* __restrict__ g_batch, const int* __restrict__ s_batch,
                            int* __restrict__ starts, RepArgs ra, int total_groups) {
    int t = blockIdx.x * blockDim.x + threadIdx.x;
    if (t < NT * 16) {
        size_t e = (size_t)t * 4;
        const float* src = (e < (size_t)N_G * 64) ? (gx + e) : (sx + (e - (size_t)N_G * 64));
        floatx4 v = *(const floatx4*)src;
        int w8 = 0;
        w8 = __builtin_amdgcn_cvt_pk_fp8_f32(v[0], v[1], w8, false);
        w8 = __builtin_amdgcn_cvt_pk_fp8_f32(v[2], v[3], w8, true);
        *(unsigned int*)(X0_8 + e) = (unsigned int)w8;
    }
    if (t < NT) dcount[t] = 0;
    if (t < 16 * 192) pooled[t] = 0.f;
    if (t <= 16) {
        int b = t;
        if (b == 16) { starts[16] = NT; }
        else {
            int key, n, base;
            const int* arr;
            if (b < 8) { arr = g_batch; n = N_G; key = b; base = 0; }
            else       { arr = s_batch; n = N_S; key = b - 8; base = N_G; }
            int lo = 0, hi = n;
            while (lo < hi) { int mid = (lo + hi) >> 1; if (arr[mid] < key) lo = mid + 1; else hi = mid; }
            starts[b] = base + lo;
        }
    }
    // weight repack: fp32 [o][c] -> bf16 MFMA-fragment order
    if (t < total_groups) {
        int seg = 0, off = t;
        while (seg < 5 && off >= ra.groups[seg]) { off -= ra.groups[seg]; ++seg; }
        int CIN = ra.cin[seg], NK = ra.nk[seg];
        int lane = off & 63;
        int rest = off >> 6;
        int tt = rest % NK;
        int ot = rest / NK;
        int o = ot * 16 + (lane & 15);
        int kk = tt * 32 + (lane >> 4) * 8;
        const float* src = (kk < CIN) ? (ra.Wr[seg] + (size_t)o * CIN + kk)
                                      : (ra.Wn[seg] + (size_t)o * CIN + (kk - CIN));
        floatx4 u0 = *(const floatx4*)src;
        floatx4 u1 = *(const floatx4*)(src + 4);
        short8 d;
        d[0]=f2b(u0[0]); d[1]=f2b(u0[1]); d[2]=f2b(u0[2]); d[3]=f2b(u0[3]);
        d[4]=f2b(u1[0]); d[5]=f2b(u1[1]); d[6]=f2b(u1[2]); d[7]=f2b(u1[3]);
        *(short8*)(ra.dst[seg] + (size_t)off * 8) = d;
    }
}

// ---------------- stride-CSR fill: XCD-aligned dst groups ----------------
__global__ void fill_kernel(const int* __restrict__ g_ei, const int* __restrict__ s_ei,
                            int* __restrict__ dcount, int* __restrict__ csr) {
    int pass = blockIdx.x & (FPASS - 1);
    int lb   = blockIdx.x >> 3;
    int t = lb * blockDim.x + threadIdx.x;
    if (t >= ET) return;
    int dst;
    if (t < E_G) dst = g_ei[E_G + t];
    else         dst = s_ei[E_S + (t - E_G)] + N_G;
    int lo = pass * (NT / FPASS);
    int hi = lo + (NT / FPASS);
    if (dst < lo || dst >= hi) return;
    int src;
    if (t < E_G) src = g_ei[t];
    else         src = s_ei[t - E_G] + N_G;
    int slot = atomicAdd(&dcount[dst], 1);
    if (slot < STRIDE) csr[(size_t)dst * STRIDE + slot] = src;
}

// ---------------- fp8 gather aggregation (all layers); bf16 out -------------
template<int C>
__global__ void agg8_kernel(const unsigned char* __restrict__ x8, const int* __restrict__ dcount,
                            const int* __restrict__ csr, short* __restrict__ out) {
    constexpr int C16 = C / 16;
    int t = blockIdx.x * blockDim.x + threadIdx.x;
    if (t >= NT * C16) return;
    int node = t / C16;
    int ch   = t % C16;
    int e0 = node * STRIDE;
    int e1 = e0 + min(dcount[node], STRIDE);
    float acc[16];
    #pragma unroll
    for (int j = 0; j < 16; ++j) acc[j] = 0.f;
    for (int e = e0; e < e1; ++e) {
        int s = csr[e];
        intx4 w = *(const intx4*)(x8 + (size_t)s * C + ch * 16);
        #pragma unroll
        for (int q = 0; q < 4; ++q) {
            floatx2 f0 = __builtin_amdgcn_cvt_pk_f32_fp8(w[q], false);
            floatx2 f1 = __builtin_amdgcn_cvt_pk_f32_fp8(w[q], true);
            acc[q * 4 + 0] += f0[0];
            acc[q * 4 + 1] += f0[1];
            acc[q * 4 + 2] += f1[0];
            acc[q * 4 + 3] += f1[1];
        }
    }
    short8 o0, o1;
    #pragma unroll
    for (int j = 0; j < 8; ++j) { o0[j] = f2b(acc[j]); o1[j] = f2b(acc[8 + j]); }
    short8* q = (short8*)(out + (size_t)node * C + ch * 16);
    q[0] = o0; q[1] = o1;
}

// ---------------- dual-GEMM + bias + ELU; barrier-free col-split ------------
// v4: one wave per (row-tile, col-slice); block = 128 thr = 2 row-tiles of
// the SAME slice (wave pair shares weight addresses -> L1 reuse). No LDS,
// no barriers: occupancy VGPR-capped, every wave makes independent memory
// progress. Weights stream from L2 (596KB total, permanently L2-hot).
// XCD-affine swizzle: all C slices of a row-group land on the SAME XCD in
// adjacent slots -> A re-reads are L2-hits. Per-wave g/s branch selection.
template<int CIN, int COUT, int C, bool POOL>
__global__ __launch_bounds__(128, 5) void gemm_elu_kernel(
        const short* __restrict__ A1, const unsigned char* __restrict__ A2_8,
        const short* __restrict__ gWF, const short* __restrict__ sWF,
        const float* __restrict__ gB, const float* __restrict__ sB,
        unsigned char* __restrict__ out8,
        float* __restrict__ pooled, const int* __restrict__ starts) {
    constexpr int NK  = CIN / 16;            // k-chunks (K = 2*CIN, 32 per MFMA)
    constexpr int NOT = COUT / 16;
    constexpr int OTW = NOT / C;             // output tiles per wave
    static_assert(NOT % C == 0, "C must divide NOT");
    constexpr int KH  = (NK > 8) ? 2 : 1;    // k-split halves A register pressure
    constexpr int NKH = NK / KH;
    constexpr int NTILE = NT / 16;           // 3750 (even)
    constexpr int RG = NTILE / 2;            // 1875 row-groups of 2 tiles
    constexpr int TSUB = N_G / 16;           // 3125: first subgraph tile

    // decode: bx = ((rghi*C + c) << 3) | rg8 ; rg = rghi*8 + rg8
    int rg8 = blockIdx.x & 7;
    int rest = blockIdx.x >> 3;
    int c = rest % C;
    int rg = (rest / C) * 8 + rg8;
    if (rg >= RG) return;                    // no barriers -> safe early exit

    int wid = threadIdx.x >> 6;
    int lane = threadIdx.x & 63;
    int id = lane & 15, quad = lane >> 4;
    int tile = rg * 2 + wid;                 // < 3750 always
    bool sub = (tile >= TSUB);               // per-wave uniform
    const short* WFl = sub ? sWF : gWF;
    const float* bias = sub ? sB : gB;
    int r0 = tile * 16;
    int arow = r0 + id;

    int seg0 = 0, seg1 = 0;
    if (POOL) {
        while (seg0 < 15 && starts[seg0 + 1] <= r0) ++seg0;
        seg1 = seg0;
        while (seg1 < 15 && starts[seg1 + 1] <= r0 + 15) ++seg1;
    }

    floatx4 acc[OTW];
    #pragma unroll
    for (int o = 0; o < OTW; ++o) acc[o] = floatx4{0.f, 0.f, 0.f, 0.f};

    for (int kh = 0; kh < KH; ++kh) {
        short8 a[NKH];                       // A: m=lane&15, k=quad*8+j
        #pragma unroll
        for (int t = 0; t < NKH; ++t) {
            int kk = (kh * NKH + t) * 32 + quad * 8;
            if (kk < CIN) {
                a[t] = *(const short8*)(A1 + (size_t)arow * CIN + kk);
            } else {
                intx2 w = *(const intx2*)(A2_8 + (size_t)arow * CIN + (kk - CIN));
                a[t] = fp8x8_to_bf16(w);
            }
        }
        #pragma unroll
        for (int otl = 0; otl < OTW; ++otl) {
            const short* wp = WFl + ((((size_t)(c * OTW + otl) * NK + kh * NKH) * 64) + lane) * 8;
            #pragma unroll
            for (int t = 0; t < NKH; ++t) {
                short8 b = *(const short8*)(wp + (size_t)t * 512);  // 1KB/wave, L2/L1-hot
                acc[otl] = __builtin_amdgcn_mfma_f32_16x16x32_bf16(a[t], b, acc[otl], 0, 0, 0);
            }
        }
    }

    // epilogue
    #pragma unroll
    for (int otl = 0; otl < OTW; ++otl) {
        int o = (c * OTW + otl) * 16 + id;
        float bv = bias[o];
        float vr[4];
        #pragma unroll
        for (int rr = 0; rr < 4; ++rr) {
            float v = acc[otl][rr] + bv;
            vr[rr] = (v > 0.f) ? v : (__expf(v) - 1.f);
        }
        if (!POOL) {
            #pragma unroll
            for (int rr = 0; rr < 4; ++rr) {
                int nrow = r0 + quad * 4 + rr;   // C/D: col=lane&15, row=quad*4+reg
                int w8 = __builtin_amdgcn_cvt_pk_fp8_f32(vr[rr], vr[rr], 0, false);
                out8[(size_t)nrow * COUT + o] = (unsigned char)(w8 & 0xFF);
            }
        } else if (seg0 == seg1) {
            float vsum = vr[0] + vr[1] + vr[2] + vr[3];
            vsum += __shfl_down(vsum, 32, 64);
            vsum += __shfl_down(vsum, 16, 64);
            if (lane < 16) atomicAdd(&pooled[seg0 * 192 + o], vsum);
        } else {
            #pragma unroll
            for (int rr = 0; rr < 4; ++rr) {
                int nrow = r0 + quad * 4 + rr;
                int sg = seg0;
                while (sg < seg1 && starts[sg + 1] <= nrow) ++sg;
                atomicAdd(&pooled[sg * 192 + o], vr[rr]);
            }
        }
    }
}

// ---------------- MLP layer 1: one wave per (b,o); builds x on the fly ----------
__global__ __launch_bounds__(256) void mlp1_kernel(
        const float* __restrict__ pooled, const int* __restrict__ starts,
        const float* __restrict__ point, const float* __restrict__ W,
        const float* __restrict__ bias, float* __restrict__ out) {
    int wave = (blockIdx.x * blockDim.x + threadIdx.x) >> 6;
    int lane = threadIdx.x & 63;
    if (wave >= BATCH * 600) return;
    int b = wave / 600, o = wave % 600;
    float invg = 1.f / (float)max(starts[b + 1] - starts[b], 1);
    float invs = 1.f / (float)max(starts[9 + b] - starts[8 + b], 1);
    const float* w = W + (size_t)o * 448;
    float acc = 0.f;
    for (int i = lane; i < 448; i += 64) {
        float x;
        if (i < 192)      x = pooled[b * 192 + i] * invg;
        else if (i < 384) x = pooled[(8 + b) * 192 + (i - 192)] * invs;
        else              x = point[b * 64 + (i - 384)];
        acc += x * w[i];
    }
    #pragma unroll
    for (int off = 32; off > 0; off >>= 1) acc += __shfl_down(acc, off, 64);
    if (lane == 0) out[wave] = fmaxf(acc + bias[o], 0.f);
}

// ---------------- dense layer: one wave per output neuron ----------------
__global__ __launch_bounds__(256) void dense_wave_kernel(
        const float* __restrict__ in, const float* __restrict__ W,
        const float* __restrict__ bias, float* __restrict__ out,
        int I, int O, int relu) {
    int wave = (blockIdx.x * blockDim.x + threadIdx.x) >> 6;
    int lane = threadIdx.x & 63;
    if (wave >= BATCH * O) return;
    int b = wave / O, o = wave % O;
    const float* x = in + (size_t)b * I;
    const float* w = W + (size_t)o * I;
    float acc = 0.f;
    for (int i = lane; i < I; i += 64) acc += x[i] * w[i];
    #pragma unroll
    for (int off = 32; off > 0; off >>= 1) acc += __shfl_down(acc, off, 64);
    if (lane == 0) {
        acc += bias[o];
        if (relu) acc = fmaxf(acc, 0.f);
        out[wave] = acc;
    }
}

extern "C" void kernel_launch(void* const* d_in, const int* in_sizes, int n_in,
                              void* d_out, int out_size, void* d_ws, size_t ws_size,
                              hipStream_t stream) {
    const float* graph_x = (const float*)d_in[0];
    const float* sub_x   = (const float*)d_in[1];
    const float* point   = (const float*)d_in[2];
    const int*   g_ei    = (const int*)d_in[3];
    const int*   g_batch = (const int*)d_in[4];
    const int*   s_ei    = (const int*)d_in[5];
    const int*   s_batch = (const int*)d_in[6];
    const float* gB1=(const float*)d_in[9],  *gB2=(const float*)d_in[12], *gB3=(const float*)d_in[15];
    const float* sB1=(const float*)d_in[18], *sB2=(const float*)d_in[21], *sB3=(const float*)d_in[24];
    const float* l1W=(const float*)d_in[25], *l1b=(const float*)d_in[26];
    const float* l2W=(const float*)d_in[27], *l2b=(const float*)d_in[28];
    const float* l3W=(const float*)d_in[29], *l3b=(const float*)d_in[30];

    char* ws = (char*)d_ws;
    size_t off = 0;
    auto alloc = [&](size_t bytes) -> char* {
        char* p = ws + off;
        off = (off + bytes + 255) & ~(size_t)255;
        return p;
    };
    int* dcount = (int*)alloc((size_t)NT * 4);
    int* csr = (int*)alloc((size_t)NT * STRIDE * 4);   // 15.36 MB stride-CSR

    // fragment-ordered bf16 weight slab: per layer COUT*2*CIN elems
    const int fsz[3] = {128 * 2 * 64, 256 * 2 * 128, 192 * 2 * 256};
    short* wfrag = (short*)alloc((size_t)(fsz[0] + fsz[1] + fsz[2]) * 2 * 2);
    short* gWF[3], *sWF[3];
    { size_t o2 = 0;
      for (int l = 0; l < 3; ++l) { gWF[l] = wfrag + o2; o2 += fsz[l]; }
      for (int l = 0; l < 3; ++l) { sWF[l] = wfrag + o2; o2 += fsz[l]; } }

    unsigned char* X0_8 = (unsigned char*)alloc((size_t)NT * 64);
    short* agg = (short*)alloc((size_t)NT * 256 * 2);
    unsigned char* h1_8 = (unsigned char*)alloc((size_t)NT * 128);
    unsigned char* h2_8 = (unsigned char*)alloc((size_t)NT * 256);

    float* pooled = (float*)alloc(16 * 192 * 4);
    int* starts = (int*)alloc(17 * 4);
    float* mlp_h1 = (float*)alloc(BATCH * 600 * 4);
    float* mlp_h2 = (float*)alloc(BATCH * 256 * 4);

    // weight repack args (merged into init)
    RepArgs ra;
    const int cin_l[3] = {64, 128, 256};
    const int nk_l[3]  = {4, 8, 16};
    const int not_l[3] = {8, 16, 12};
    const int wr_idx[6] = {7, 10, 13, 16, 19, 22};
    int total_groups = 0;
    for (int s = 0; s < 6; ++s) {
        int l = s % 3;
        ra.Wr[s] = (const float*)d_in[wr_idx[s]];
        ra.Wn[s] = (const float*)d_in[wr_idx[s] + 1];
        ra.dst[s] = (s < 3) ? gWF[l] : sWF[l];
        ra.cin[s] = cin_l[l];
        ra.nk[s] = nk_l[l];
        ra.groups[s] = not_l[l] * nk_l[l] * 64;
        total_groups += ra.groups[s];
    }

    init_kernel<<<(NT * 16 + 255) / 256, 256, 0, stream>>>(graph_x, sub_x, X0_8, dcount,
                                                           pooled, g_batch, s_batch, starts,
                                                           ra, total_groups);

    fill_kernel<<<((ET + 255) / 256) * FPASS, 256, 0, stream>>>(g_ei, s_ei, dcount, csr);

    // gemm grids: 235*8 row-slots x C slices, 128-thread blocks
    // L1 C=2: 3760 blocks; L2 C=4: 7520; L3 C=4: 7520
    agg8_kernel<64><<<(NT * 4 + 255) / 256, 256, 0, stream>>>(X0_8, dcount, csr, agg);
    gemm_elu_kernel<64, 128, 2, false><<<235 * 2 * 8, 128, 0, stream>>>(
        agg, X0_8, gWF[0], sWF[0], gB1, sB1, h1_8, nullptr, nullptr);
    agg8_kernel<128><<<(NT * 8 + 255) / 256, 256, 0, stream>>>(h1_8, dcount, csr, agg);
    gemm_elu_kernel<128, 256, 4, false><<<235 * 4 * 8, 128, 0, stream>>>(
        agg, h1_8, gWF[1], sWF[1], gB2, sB2, h2_8, nullptr, nullptr);
    agg8_kernel<256><<<(NT * 16 + 255) / 256, 256, 0, stream>>>(h2_8, dcount, csr, agg);
    gemm_elu_kernel<256, 192, 4, true><<<235 * 4 * 8, 128, 0, stream>>>(
        agg, h2_8, gWF[2], sWF[2], gB3, sB3, nullptr, pooled, starts);

    mlp1_kernel<<<(BATCH * 600 + 3) / 4, 256, 0, stream>>>(pooled, starts, point, l1W, l1b, mlp_h1);
    dense_wave_kernel<<<(BATCH * 256 + 3) / 4, 256, 0, stream>>>(mlp_h1, l2W, l2b, mlp_h2, 600, 256, 1);
    dense_wave_kernel<<<(BATCH * 64 + 3) / 4, 256, 0, stream>>>(mlp_h2, l3W, l3b, (float*)d_out, 256, 64, 0);
}